// Round 6
// baseline (43523.825 us; speedup 1.0000x reference)
//
#include <hip/hip_runtime.h>
#include <stdint.h>

#define BB 64
#define TT 512
#define II 512
#define HH 1024
#define OO 512
#define KC 128            // k per LDS chunk
#define NSL 32            // float4-slots per chunk
#define NCH 12            // (II+HH)/KC ; chunks 0..3 = x, 4..11 = h
#define NBLK 256
#define NTHR 1024
#define NWAVE 16
#define HSLOT (BB * HH)   // 65536 floats per h ring slot

// ws float layout: control | f16 weights | h ring
#define WS_ROOT 0
#define WS_GRP  32                        // 8 counters, 32-float padded
#define WS_CTRL_FLOATS 288
#define WS_WGT  288                       // f16 gate weights (uint4-packed)
#define WS_WGT_FLOATS (NBLK * 384 * 8 * 4)    // 3,145,728 floats (12.6 MB)
#define WS_RING (WS_WGT + WS_WGT_FLOATS)      // 3,146,016
#define WS_RING_SLOTS 513
#define WS_NEEDED_BYTES ((size_t)(WS_RING + (size_t)WS_RING_SLOTS * HSLOT) * 4)

// LDS float layout
#define L_COMB0 0                         // 8192
#define L_COMB1 (KC*BB)                   // 8192..16384
#define L_GPART (2*KC*BB)                 // 16 waves * 16 vals * 64 lanes = 16384
#define L_YBUF  (L_GPART + 16*16*64)      // 16*2*64 = 2048
#define L_HGATH (L_YBUF + 2048)           // 256
#define L_NFLOATS (L_HGATH + 256)         // 35456 floats = 141824 B

typedef _Float16 h2 __attribute__((ext_vector_type(2)));

#if __has_builtin(__builtin_amdgcn_fdot2)
#define FDOT2(a,b,c) __builtin_amdgcn_fdot2((a),(b),(c),false)
#else
static __device__ __forceinline__ float FDOT2(h2 a, h2 b, float c) {
  return fmaf((float)a.x, (float)b.x, fmaf((float)a.y, (float)b.y, c));
}
#endif

static __device__ __forceinline__ h2 bc_h2(uint32_t v) { return __builtin_bit_cast(h2, v); }
static __device__ __forceinline__ h2 pkrtz(float a, float b) {
  return __builtin_bit_cast(h2, __builtin_amdgcn_cvt_pkrtz(a, b));
}

__device__ __forceinline__ float sigm(float v) { return 1.0f / (1.0f + __expf(-v)); }
__device__ __forceinline__ float tanh_c(float v) {
  v = fminf(fmaxf(v, -20.0f), 20.0f);
  float e = __expf(-2.0f * v);
  return (1.0f - e) / (1.0f + e);
}

// agent-scope (sc0 sc1) 8B load/store: per-access coherence, no cache-wide ops
__device__ __forceinline__ float2 cohere_ld8(const float* p) {
  unsigned long long q = __hip_atomic_load((const unsigned long long*)p,
                                           __ATOMIC_RELAXED, __HIP_MEMORY_SCOPE_AGENT);
  return __builtin_bit_cast(float2, q);
}
__device__ __forceinline__ void cohere_st8(float* p, float a, float b) {
  float2 v = make_float2(a, b);
  __hip_atomic_store((unsigned long long*)p, __builtin_bit_cast(unsigned long long, v),
                     __ATOMIC_RELAXED, __HIP_MEMORY_SCOPE_AGENT);
}

__device__ __forceinline__ void grid_barrier(uint32_t* grpc, uint32_t* rootc,
                                             uint32_t grp_target, uint32_t root_target) {
  asm volatile("s_waitcnt vmcnt(0)" ::: "memory");
  __syncthreads();
  if (threadIdx.x == 0) {
    uint32_t old = __hip_atomic_fetch_add(grpc, 1u, __ATOMIC_RELAXED, __HIP_MEMORY_SCOPE_AGENT);
    if (old == grp_target - 1u)
      __hip_atomic_fetch_add(rootc, 1u, __ATOMIC_RELAXED, __HIP_MEMORY_SCOPE_AGENT);
    while (__hip_atomic_load(rootc, __ATOMIC_RELAXED, __HIP_MEMORY_SCOPE_AGENT) < root_target)
      __builtin_amdgcn_s_sleep(2);
  }
  __syncthreads();
}

// -------- preprocess: fp32 gate weights -> f16, gate-interleaved --------
__global__ void __launch_bounds__(256) wprep(
    const float* __restrict__ Wf, const float* __restrict__ Wi,
    const float* __restrict__ Wc, const float* __restrict__ Wo,
    float* __restrict__ ws)
{
  int idx = blockIdx.x * 256 + threadIdx.x;       // blk*384 + sg
  if (idx >= NBLK * 384) return;
  int blkk = idx / 384, sg = idx % 384;
  uint4* dst = (uint4*)(ws + WS_WGT) + (size_t)idx * 8;
  const float* Ws[4] = {Wf, Wi, Wc, Wo};
  #pragma unroll
  for (int u = 0; u < 4; ++u) {
    int row = blkk * 4 + u;
    uint32_t p[8];
    #pragma unroll
    for (int g = 0; g < 4; ++g) {
      const float* src = Ws[g] + (size_t)row * 1536 + sg * 4;
      h2 lo; lo.x = (_Float16)src[0]; lo.y = (_Float16)src[1];   // RNE
      h2 hi; hi.x = (_Float16)src[2]; hi.y = (_Float16)src[3];
      p[g*2+0] = __builtin_bit_cast(uint32_t, lo);
      p[g*2+1] = __builtin_bit_cast(uint32_t, hi);
    }
    dst[u*2+0] = make_uint4(p[0], p[1], p[2], p[3]);
    dst[u*2+1] = make_uint4(p[4], p[5], p[6], p[7]);
  }
}

// -------- staging helpers --------
// h reads: ring mode -> PLAIN cached loads from a virgin (never-reused)
// step-indexed slot; addresses were never cached anywhere, so the cold miss
// pulls the sc1-written data from L3 and lets the 32 blocks of an XCD share
// one L2 fill (h fetch 64 MB/step -> 2 MB/step). Fallback: bypass loads.
#define ISSUE(vv, kcn) { \
    const int koff_ = (kcn) * KC; \
    _Pragma("unroll") \
    for (int i_ = 0; i_ < 2; ++i_) { \
      const int bs_ = (tid >> 5) + i_ * 32; \
      const int sl_ = tid & 31; \
      if (koff_ < II) { \
        vv[i_] = *(const float4*)(x + (size_t)bs_ * (TT*II) + (size_t)xit * II + koff_ + sl_ * 4); \
      } else { \
        const float* sp_ = hprev + (size_t)bs_ * HH + (koff_ - II) + sl_ * 4; \
        if (use_ring) { \
          vv[i_] = *(const float4*)sp_; \
        } else { \
          float2 lo_ = cohere_ld8(sp_); float2 hi_ = cohere_ld8(sp_ + 2); \
          vv[i_] = make_float4(lo_.x, lo_.y, hi_.x, hi_.y); \
        } \
      } \
    } }

#define WRITE(vv, kcn) { \
    float4* dstb_ = (float4*)(lds + (((kcn) & 1) ? L_COMB1 : L_COMB0)); \
    _Pragma("unroll") \
    for (int i_ = 0; i_ < 2; ++i_) { \
      const int bs_ = (tid >> 5) + i_ * 32; \
      const int sl_ = tid & 31; \
      dstb_[bs_ * NSL + (sl_ ^ (bs_ & 15))] = vv[i_]; \
    } }

__global__ void __launch_bounds__(NTHR, 4)
lstm_kernel(const float* __restrict__ x,
            const float* __restrict__ bf, const float* __restrict__ bi,
            const float* __restrict__ bc, const float* __restrict__ bo,
            const float* __restrict__ Wfc, const float* __restrict__ bfc,
            float* __restrict__ out, float* __restrict__ ws, int use_ring)
{
  extern __shared__ float lds[];
  const int tid  = threadIdx.x;
  const int blk  = blockIdx.x;
  const int wave = tid >> 6;
  const int lane = tid & 63;
  const int b    = lane;
  const int mm   = b & 15;

  uint32_t* rootc = (uint32_t*)ws + WS_ROOT;
  uint32_t* grpc  = (uint32_t*)ws + WS_GRP + (blk & 7) * 32;
  float* hring = ws + WS_RING;
  const uint4* wgt = (const uint4*)(ws + WS_WGT) + (size_t)blk * 384 * 8;

  const int ub = __builtin_amdgcn_readfirstlane(blk * 4 + (wave & 3));
  const float bsf = bf[ub], bsi = bi[ub], bsc = bc[ub], bso = bo[ub];

  const float* rowy0 = Wfc + (size_t)(blk * 2 + 0) * HH;
  const float* rowy1 = Wfc + (size_t)(blk * 2 + 1) * HH;

  float cstate = 0.0f, hlast = 0.0f;     // valid on waves 0-3

  for (int it = 0; it <= TT; ++it) {
    const int rs = use_ring ? it : (it & 1);
    const int wslt = use_ring ? (it + 1) : ((it + 1) & 1);
    const float* hprev = hring + (size_t)rs * HSLOT;
    float*       hnext = hring + (size_t)wslt * HSLOT;
    const int xit = (it < TT) ? it : 0;

    float ag[4][4];
    #pragma unroll
    for (int u = 0; u < 4; ++u)
      #pragma unroll
      for (int g = 0; g < 4; ++g) ag[u][g] = 0.0f;
    float ay0 = 0.0f, ay1 = 0.0f;

    float4 vsA[2], vsB[2];
    ISSUE(vsA, 0); ISSUE(vsB, 1);
    WRITE(vsA, 0);
    __syncthreads();

    #pragma unroll
    for (int kc = 0; kc < NCH; ++kc) {
      if (kc + 2 < NCH) {
        if (kc & 1) { ISSUE(vsB, kc + 2); } else { ISSUE(vsA, kc + 2); }
      }

      {
        const float4* cbf4 = (const float4*)(lds + ((kc & 1) ? L_COMB1 : L_COMB0));
        #pragma unroll
        for (int sl = 0; sl < 2; ++sl) {
          const int s  = 2 * wave + sl;
          const int sg = kc * NSL + s;
          float4 cv = cbf4[b * NSL + (s ^ mm)];
          if (it < TT) {
            h2 a01 = pkrtz(cv.x, cv.y);
            h2 a23 = pkrtz(cv.z, cv.w);
            const uint4* wv = wgt + (size_t)sg * 8;
            #pragma unroll
            for (int u = 0; u < 4; ++u) {
              uint4 q0 = wv[u*2+0];
              uint4 q1 = wv[u*2+1];
              ag[u][0] = FDOT2(a23, bc_h2(q0.y), FDOT2(a01, bc_h2(q0.x), ag[u][0]));
              ag[u][1] = FDOT2(a23, bc_h2(q0.w), FDOT2(a01, bc_h2(q0.z), ag[u][1]));
              ag[u][2] = FDOT2(a23, bc_h2(q1.y), FDOT2(a01, bc_h2(q1.x), ag[u][2]));
              ag[u][3] = FDOT2(a23, bc_h2(q1.w), FDOT2(a01, bc_h2(q1.z), ag[u][3]));
            }
          }
          if (kc >= 4 && it > 0) {       // y over h-part, fp32 (shares cv read)
            const int kh = sg * 4 - II;
            float4 wy0 = *(const float4*)(rowy0 + kh);
            float4 wy1 = *(const float4*)(rowy1 + kh);
            ay0 += cv.x*wy0.x + cv.y*wy0.y + cv.z*wy0.z + cv.w*wy0.w;
            ay1 += cv.x*wy1.x + cv.y*wy1.y + cv.z*wy1.z + cv.w*wy1.w;
          }
        }
      }

      if (kc + 1 < NCH) {
        if (kc & 1) { WRITE(vsA, kc + 1); } else { WRITE(vsB, kc + 1); }
        __syncthreads();
      }
    }

    // ---- publish partials (wave-major: stride-1 in b, conflict-free) ----
    if (it < TT) {
      #pragma unroll
      for (int u = 0; u < 4; ++u)
        #pragma unroll
        for (int g = 0; g < 4; ++g)
          lds[L_GPART + (wave * 16 + u * 4 + g) * 64 + b] = ag[u][g];
    }
    if (it > 0) {
      lds[L_YBUF + wave*128 + 0*64 + b] = ay0;
      lds[L_YBUF + wave*128 + 1*64 + b] = ay1;
    }
    __syncthreads();

    // ---- gate combine + state update (waves 0-3; wave == ul) ----
    if (it < TT && wave < 4) {
      float t[4] = {0.f, 0.f, 0.f, 0.f};
      #pragma unroll
      for (int w = 0; w < 16; ++w) {
        #pragma unroll
        for (int g = 0; g < 4; ++g)
          t[g] += lds[L_GPART + (w * 16 + wave * 4 + g) * 64 + b];
      }
      float gf = sigm(t[0] + bsf);
      float gi = sigm(t[1] + bsi);
      float gc = tanh_c(t[2] + bsc);
      float go = sigm(t[3] + bso);
      cstate = gf * cstate + gi * gc;
      float hv = go * tanh_c(cstate);
      hlast = hv;
      lds[L_HGATH + b*4 + wave] = hv;
    }

    // ---- y output for step it-1 (NT stores) ----
    if (it > 0 && tid < 2 * BB) {
      int q  = tid >> 6;
      int qb = tid & 63;
      float yv = bfc[blk*2 + q];
      #pragma unroll
      for (int w = 0; w < 16; ++w)
        yv += lds[L_YBUF + w*128 + q*64 + qb];
      __builtin_nontemporal_store(yv,
          &out[(size_t)qb * (TT*OO) + (size_t)(it-1) * OO + (blk*2 + q)]);
    }
    __syncthreads();

    // ---- coalesced h store: wave0, sc1 write-through (lands in L3) ----
    if (it < TT && wave == 0) {
      float4 hq = *(const float4*)(lds + L_HGATH + b*4);
      float* hp = hnext + (size_t)b * HH + blk*4;
      cohere_st8(hp + 0, hq.x, hq.y);
      cohere_st8(hp + 2, hq.z, hq.w);
    }

    // ---- final h/c from registers ----
    if (it == TT && wave < 4) {
      out[(size_t)(BB*TT*OO) + (size_t)b * HH + (blk*4 + wave)] = hlast;
      out[(size_t)(BB*TT*OO + BB*HH) + (size_t)b * HH + (blk*4 + wave)] = cstate;
    }

    if (it < TT)
      grid_barrier(grpc, rootc, 32u * (uint32_t)(it + 1), 8u * (uint32_t)(it + 1));
  }
}

extern "C" void kernel_launch(void* const* d_in, const int* in_sizes, int n_in,
                              void* d_out, int out_size, void* d_ws, size_t ws_size,
                              hipStream_t stream) {
  (void)in_sizes; (void)n_in; (void)out_size;
  const float* x   = (const float*)d_in[0];
  const float* Wf  = (const float*)d_in[1];
  const float* bf  = (const float*)d_in[2];
  const float* Wi  = (const float*)d_in[3];
  const float* bi  = (const float*)d_in[4];
  const float* Wc  = (const float*)d_in[5];
  const float* bc  = (const float*)d_in[6];
  const float* Wo  = (const float*)d_in[7];
  const float* bo  = (const float*)d_in[8];
  const float* Wfc = (const float*)d_in[9];
  const float* bfc = (const float*)d_in[10];
  float* out = (float*)d_out;
  float* ws  = (float*)d_ws;

  int use_ring = (ws_size >= WS_NEEDED_BYTES) ? 1 : 0;

  // zero barrier counters + ring slot 0 (h0 = 0) each call
  hipMemsetAsync(d_ws, 0, (size_t)WS_CTRL_FLOATS * sizeof(float), stream);
  hipMemsetAsync(ws + WS_RING, 0, (size_t)HSLOT * sizeof(float), stream);

  // fp32 -> f16 interleaved weight pack
  wprep<<<dim3((NBLK*384 + 255)/256), dim3(256), 0, stream>>>(Wf, Wi, Wc, Wo, ws);

  hipFuncSetAttribute((const void*)lstm_kernel,
                      hipFuncAttributeMaxDynamicSharedMemorySize,
                      (int)(L_NFLOATS * sizeof(float)));

  void* args[] = { &x, &bf, &bi, &bc, &bo, &Wfc, &bfc, &out, &ws, &use_ring };
  hipLaunchCooperativeKernel(reinterpret_cast<void*>(lstm_kernel),
                             dim3(NBLK), dim3(NTHR), args,
                             (unsigned)(L_NFLOATS * sizeof(float)), stream);
}

// Round 7
// 11822.219 us; speedup vs baseline: 3.6815x; 3.6815x over previous
//
#include <hip/hip_runtime.h>
#include <stdint.h>

#define BB 64
#define TT 512
#define II 512
#define HH 1024
#define OO 512
#define NBLK 256
#define NTHR 512
#define GG 4            // batch groups (16 batches each)
#define SS 64           // unit slices (16 units each)
#define NB 16           // batches per group
#define US 16           // units per slice
#define NROW 64         // gate rows per slice (US*4)
#define NKOCT 192       // K octets: (II+HH)/8
#define KOCT_PW 24      // K octets per wave (192/8)
#define ASTR 1544       // act row stride in fp16 (1536 + 8 pad)

// ws float-offsets
#define WS_CTRL 0            // 1280 floats: root[g] @ g*32 ; sub[g][x] @ 128+(g*8+x)*32
#define WS_HBUF 1280         // 2 slots x (64*1024) fp16 = 65536 floats
#define WS_WSLAB 66816       // SS*NKOCT*64 uint4 = 12.58 MB = 3145728 floats
#define WS_WFC16 3212544     // 512*1024 fp16 = 262144 floats
#define WS_TOTAL 3474688     // 13.9 MB
#define BTO (BB*TT*OO)
#define BH  (BB*HH)

// LDS: acts [16][ASTR] fp16 (49408 B) | part [8][64][17] fp32 (34816 B)
#define L_PART_OFF 12352     // float index of part
#define L_TOTAL_BYTES 84224

typedef _Float16 h2 __attribute__((ext_vector_type(2)));

#if __has_builtin(__builtin_amdgcn_fdot2)
#define FDOT2(a,b,c) __builtin_amdgcn_fdot2((a),(b),(c),false)
#else
static __device__ __forceinline__ float FDOT2(h2 a, h2 b, float c) {
  return fmaf((float)a.x, (float)b.x, fmaf((float)a.y, (float)b.y, c));
}
#endif

static __device__ __forceinline__ h2 bc_h2(uint32_t v) { return __builtin_bit_cast(h2, v); }
static __device__ __forceinline__ uint32_t pk_u32(float a, float b) {
  return __builtin_bit_cast(uint32_t, __builtin_amdgcn_cvt_pkrtz(a, b));
}

__device__ __forceinline__ float sigm(float v) { return 1.0f / (1.0f + __expf(-v)); }
__device__ __forceinline__ float tanh_c(float v) {
  v = fminf(fmaxf(v, -20.0f), 20.0f);
  float e = __expf(-2.0f * v);
  return (1.0f - e) / (1.0f + e);
}

// agent-scope (sc0 sc1) accesses: per-access coherence, NO cache-wide ops
__device__ __forceinline__ uint2 cohere_ld8(const void* p) {
  unsigned long long q = __hip_atomic_load((const unsigned long long*)p,
                                           __ATOMIC_RELAXED, __HIP_MEMORY_SCOPE_AGENT);
  return __builtin_bit_cast(uint2, q);
}
__device__ __forceinline__ void cohere_st4(void* p, uint32_t v) {
  __hip_atomic_store((uint32_t*)p, v, __ATOMIC_RELAXED, __HIP_MEMORY_SCOPE_AGENT);
}

// -------- preprocess: pack fp16 gate slab + fp16 Wfc --------
// gate slab: idx=(s*192+koct)*64+r -> 16B of 8 fp16: W_gate[r&3][u=s*16+(r>>2)][koct*8..+8)
__global__ void __launch_bounds__(256) wprep(
    const float* __restrict__ Wf, const float* __restrict__ Wi,
    const float* __restrict__ Wc, const float* __restrict__ Wo,
    const float* __restrict__ Wfc, float* __restrict__ ws)
{
  int idx = blockIdx.x * 256 + threadIdx.x;
  const int NG = SS * NKOCT * 64;
  if (idx < NG) {
    int s = idx / (NKOCT * 64);
    int rem = idx % (NKOCT * 64);
    int koct = rem >> 6, r = rem & 63;
    int u = s * US + (r >> 2), gate = r & 3;
    const float* W = (gate == 0) ? Wf : (gate == 1) ? Wi : (gate == 2) ? Wc : Wo;
    const float* src = W + (size_t)u * 1536 + koct * 8;
    uint32_t p[4];
    #pragma unroll
    for (int j = 0; j < 4; ++j) {
      h2 t; t.x = (_Float16)src[2*j]; t.y = (_Float16)src[2*j+1];   // RNE
      p[j] = __builtin_bit_cast(uint32_t, t);
    }
    ((uint4*)(ws + WS_WSLAB))[idx] = make_uint4(p[0], p[1], p[2], p[3]);
  } else if (idx < NG + 512 * 128) {
    int j2 = idx - NG;
    int o = j2 >> 7, uo = j2 & 127;
    const float* src = Wfc + (size_t)o * 1024 + uo * 8;
    uint32_t p[4];
    #pragma unroll
    for (int j = 0; j < 4; ++j) {
      h2 t; t.x = (_Float16)src[2*j]; t.y = (_Float16)src[2*j+1];
      p[j] = __builtin_bit_cast(uint32_t, t);
    }
    ((uint4*)(ws + WS_WFC16))[j2] = make_uint4(p[0], p[1], p[2], p[3]);
  }
}

// stage acts for `step`: x_step (plain cached, pkrtz) + h_{step-1} (sc1 gather)
__device__ __forceinline__ void stage_acts(const float* __restrict__ x,
                                           const ushort* __restrict__ hb16,
                                           uint4* __restrict__ acts4,
                                           int step, int b0, int tid)
{
  const int bb = tid >> 5;
  const int c5 = tid & 31;
  if (step < TT) {
    const float4* xs = (const float4*)(x + (size_t)(b0 + bb) * (TT * II)
                                         + (size_t)step * II + c5 * 16);
    float4 v0 = xs[0], v1 = xs[1], v2 = xs[2], v3 = xs[3];
    uint4 o0 = make_uint4(pk_u32(v0.x,v0.y), pk_u32(v0.z,v0.w),
                          pk_u32(v1.x,v1.y), pk_u32(v1.z,v1.w));
    uint4 o1 = make_uint4(pk_u32(v2.x,v2.y), pk_u32(v2.z,v2.w),
                          pk_u32(v3.x,v3.y), pk_u32(v3.z,v3.w));
    acts4[bb * 193 + c5 * 2]     = o0;
    acts4[bb * 193 + c5 * 2 + 1] = o1;
  }
  const int par = step & 1;
  const ushort* hs = hb16 + (size_t)par * (BB * HH) + (size_t)(b0 + bb) * HH + c5 * 32;
  uint2 q[8];
  #pragma unroll
  for (int j = 0; j < 8; ++j) q[j] = cohere_ld8(hs + j * 4);
  #pragma unroll
  for (int j = 0; j < 4; ++j)
    acts4[bb * 193 + 64 + c5 * 4 + j] = make_uint4(q[2*j].x, q[2*j].y, q[2*j+1].x, q[2*j+1].y);
}

__global__ void __launch_bounds__(NTHR, 1)
lstm_kernel(const float* __restrict__ x,
            const float* __restrict__ bf, const float* __restrict__ bi,
            const float* __restrict__ bc, const float* __restrict__ bo,
            const float* __restrict__ bfc,
            float* __restrict__ out, float* __restrict__ ws)
{
  extern __shared__ float ldsf[];
  uint4* acts4 = (uint4*)ldsf;                 // [16][193] uint4 view of acts
  float* part  = ldsf + L_PART_OFF;            // [8][64][17] fp32

  const int tid  = threadIdx.x;
  const int blk  = blockIdx.x;
  const int wave = tid >> 6;
  const int lane = tid & 63;
  const int g = blk >> 6, s = blk & 63;
  const int b0 = g * NB;
  const int u0 = s * US;

  uint32_t* ctrl = (uint32_t*)ws;
  uint32_t* rootp = ctrl + g * 32;
  uint32_t* subp  = ctrl + 128 + (g * 8 + (s & 7)) * 32;
  ushort* hb16 = (ushort*)(ws + WS_HBUF);
  const uint4* wslab = (const uint4*)(ws + WS_WSLAB);
  const uint4* wfc4  = (const uint4*)(ws + WS_WFC16);

  // state-thread persistent values (waves 0-3: bb=tid&15, ul=tid>>4)
  float cstate = 0.0f, bsf = 0.f, bsi = 0.f, bsc = 0.f, bso = 0.f;
  if (wave < 4) {
    int u = u0 + (tid >> 4);
    bsf = bf[u]; bsi = bi[u]; bsc = bc[u]; bso = bo[u];
  }
  const float ybias = bfc[s * 8 + wave];
  const size_t wbase = (size_t)s * NKOCT * 64;

  // prologue: stage acts for step 0 (x_0 + h_{-1}=0 from zeroed slot 0)
  stage_acts(x, hb16, acts4, 0, b0, tid);
  __syncthreads();

  for (int it = 0; it <= TT; ++it) {
    // ---- gate GEMM: wave w covers koct [w*24, w*24+24), lane = row ----
    if (it < TT) {
      float acc[NB];
      #pragma unroll
      for (int b = 0; b < NB; ++b) acc[b] = 0.0f;
      const int k0 = wave * KOCT_PW;
      #pragma unroll 2
      for (int i = 0; i < KOCT_PW; ++i) {
        const int koct = k0 + i;
        uint4 wq = wslab[wbase + (size_t)koct * 64 + lane];
        #pragma unroll
        for (int b = 0; b < NB; ++b) {
          uint4 av = acts4[b * 193 + koct];
          float a = acc[b];
          a = FDOT2(bc_h2(av.x), bc_h2(wq.x), a);
          a = FDOT2(bc_h2(av.y), bc_h2(wq.y), a);
          a = FDOT2(bc_h2(av.z), bc_h2(wq.z), a);
          a = FDOT2(bc_h2(av.w), bc_h2(wq.w), a);
          acc[b] = a;
        }
      }
      // publish partials: part[wave][lane][b], row len 17 (conflict-free)
      #pragma unroll
      for (int b = 0; b < NB; ++b)
        part[(wave * 64 + lane) * 17 + b] = acc[b];
    }

    // ---- y_{it-1}: wave -> o = s*8+wave; lane=(bb,uc); 256 u per lane ----
    if (it > 0) {
      const int bb = lane & 15, uc = lane >> 4;
      float yacc = 0.0f;
      const uint4* wrow = wfc4 + (size_t)(s * 8 + wave) * 128 + uc * 32;
      #pragma unroll 4
      for (int i = 0; i < 32; ++i) {
        uint4 hv = acts4[bb * 193 + 64 + uc * 32 + i];
        uint4 wv = wrow[i];
        yacc = FDOT2(bc_h2(hv.x), bc_h2(wv.x), yacc);
        yacc = FDOT2(bc_h2(hv.y), bc_h2(wv.y), yacc);
        yacc = FDOT2(bc_h2(hv.z), bc_h2(wv.z), yacc);
        yacc = FDOT2(bc_h2(hv.w), bc_h2(wv.w), yacc);
      }
      yacc += __shfl_xor(yacc, 16, 64);
      yacc += __shfl_xor(yacc, 32, 64);
      if (uc == 0)
        __builtin_nontemporal_store(yacc + ybias,
            &out[(size_t)(b0 + bb) * (TT * OO) + (size_t)(it - 1) * OO + (s * 8 + wave)]);
    }
    __syncthreads();

    // ---- reduce + state update (waves 0-3: bb=tid&15, ul=tid>>4) ----
    if (it < TT && wave < 4) {
      const int bb = tid & 15, ul = tid >> 4;
      float t0 = 0.f, t1 = 0.f, t2 = 0.f, t3 = 0.f;
      #pragma unroll
      for (int w = 0; w < 8; ++w) {
        t0 += part[(w * 64 + ul * 4 + 0) * 17 + bb];
        t1 += part[(w * 64 + ul * 4 + 1) * 17 + bb];
        t2 += part[(w * 64 + ul * 4 + 2) * 17 + bb];
        t3 += part[(w * 64 + ul * 4 + 3) * 17 + bb];
      }
      float gf = sigm(t0 + bsf);
      float gi = sigm(t1 + bsi);
      float gc = tanh_c(t2 + bsc);
      float go = sigm(t3 + bso);
      cstate = gf * cstate + gi * gc;
      float hv = go * tanh_c(cstate);

      // h -> fp16 (RNE), pack pairs across ul, sc1 store (write-through)
      uint32_t hu = (uint32_t)__builtin_bit_cast(unsigned short, (_Float16)hv);
      uint32_t other = (uint32_t)__shfl_down((int)hu, 16, 64);
      if ((ul & 1) == 0) {
        ushort* hp = hb16 + (size_t)((it + 1) & 1) * (BB * HH)
                   + (size_t)(b0 + bb) * HH + (u0 + ul);
        cohere_st4(hp, hu | (other << 16));
      }
      if (it == TT - 1) {   // final h (fp32 state) and c outputs
        out[(size_t)BTO + (size_t)(b0 + bb) * HH + (u0 + ul)] = hv;
        out[(size_t)BTO + BH + (size_t)(b0 + bb) * HH + (u0 + ul)] = cstate;
      }
    }

    // ---- group barrier, then stage acts for it+1 ----
    if (it < TT) {
      asm volatile("s_waitcnt vmcnt(0)" ::: "memory");
      __syncthreads();
      if (tid == 0) {
        uint32_t old = __hip_atomic_fetch_add(subp, 1u, __ATOMIC_RELAXED, __HIP_MEMORY_SCOPE_AGENT);
        if ((old & 7u) == 7u)
          __hip_atomic_fetch_add(rootp, 1u, __ATOMIC_RELAXED, __HIP_MEMORY_SCOPE_AGENT);
        while (__hip_atomic_load(rootp, __ATOMIC_RELAXED, __HIP_MEMORY_SCOPE_AGENT)
               < 8u * (uint32_t)(it + 1))
          __builtin_amdgcn_s_sleep(2);
      }
      __syncthreads();
      stage_acts(x, hb16, acts4, it + 1, b0, tid);
      __syncthreads();
    }
  }
}

extern "C" void kernel_launch(void* const* d_in, const int* in_sizes, int n_in,
                              void* d_out, int out_size, void* d_ws, size_t ws_size,
                              hipStream_t stream) {
  (void)in_sizes; (void)n_in; (void)out_size; (void)ws_size;
  const float* x   = (const float*)d_in[0];
  const float* Wf  = (const float*)d_in[1];
  const float* bf  = (const float*)d_in[2];
  const float* Wi  = (const float*)d_in[3];
  const float* bi  = (const float*)d_in[4];
  const float* Wc  = (const float*)d_in[5];
  const float* bc  = (const float*)d_in[6];
  const float* Wo  = (const float*)d_in[7];
  const float* bo  = (const float*)d_in[8];
  const float* Wfc = (const float*)d_in[9];
  const float* bfc = (const float*)d_in[10];
  float* out = (float*)d_out;
  float* ws  = (float*)d_ws;

  // zero barrier counters + h slot 0 (h0 = 0); deterministic per call
  hipMemsetAsync(d_ws, 0, (size_t)(WS_HBUF + BB * HH / 2) * sizeof(float), stream);

  // pack fp16 weights (gate slab + Wfc)
  const int nprep = SS * NKOCT * 64 + 512 * 128;
  wprep<<<dim3((nprep + 255) / 256), dim3(256), 0, stream>>>(Wf, Wi, Wc, Wo, Wfc, ws);

  hipFuncSetAttribute((const void*)lstm_kernel,
                      hipFuncAttributeMaxDynamicSharedMemorySize, L_TOTAL_BYTES);

  void* args[] = { &x, &bf, &bi, &bc, &bo, &bfc, &out, &ws };
  hipLaunchCooperativeKernel(reinterpret_cast<void*>(lstm_kernel),
                             dim3(NBLK), dim3(NTHR), args,
                             (unsigned)L_TOTAL_BYTES, stream);
}